// Round 1
// baseline (537.830 us; speedup 1.0000x reference)
//
#include <hip/hip_runtime.h>
#include <math.h>

// Izhikevich RS constants (match reference)
// A=0.02, Bz=0.2, C=-65, D=8, I_TONIC=-1, V_PEAK=30, RATE_DECAY=0.9
// MARGIN=50, ARENA_W=800, ARENA_H=600, PRECISION=[1,1,0.5,1]

__global__ __launch_bounds__(256) void spiking_fwd(
    const float* __restrict__ fish_x,
    const float* __restrict__ fish_y,
    const float* __restrict__ speed,
    const float* __restrict__ heading,
    const float* __restrict__ prev_x,
    const float* __restrict__ prev_y,
    const float* __restrict__ prev_heading,
    const float* __restrict__ pred_speed,
    const float* __restrict__ pred_hd,
    const float* __restrict__ v0,
    const float* __restrict__ u0,
    const float* __restrict__ noise,
    float* __restrict__ out,
    int Bn)
{
    __shared__ float sout[256 * 9];
    const int t = threadIdx.x;
    const int b = blockIdx.x * 256 + t;

    float r[9];
    if (b < Bn) {
        float fx  = fish_x[b],  fy  = fish_y[b];
        float spd = speed[b],   hdg = heading[b];
        float px  = prev_x[b],  py  = prev_y[b], phd = prev_heading[b];
        float ps  = pred_speed[b], phdd = pred_hd[b];

        float dx = fx - px, dy = fy - py;
        float actual_speed = sqrtf(dx * dx + dy * dy);

        float hd = hdg - phd;
        float heading_delta = atan2f(sinf(hd), cosf(hd));

        // max of relus == relu of max (relu is monotone)
        float wall = fmaxf(0.0f,
            fmaxf(fmaxf((50.0f - fx) / 50.0f, (fx - 750.0f) / 50.0f),
                  fmaxf((50.0f - fy) / 50.0f, (fy - 550.0f) / 50.0f)));

        float coll = (actual_speed < 1.0f && spd > 0.5f) ? 1.0f : 0.0f;

        // base currents with I_TONIC folded in
        float Ib[8];
        Ib[0] = actual_speed * 5.0f - 1.0f;
        Ib[1] = fmaxf(0.0f, 3.0f - actual_speed) * 3.0f - 1.0f;
        Ib[2] = (cosf(hdg) + 1.0f) * 3.0f - 1.0f;
        Ib[3] = (sinf(hdg) + 1.0f) * 3.0f - 1.0f;
        Ib[4] = wall * 12.0f - 1.0f;
        Ib[5] = Ib[4];
        Ib[6] = coll * 15.0f - 1.0f;
        Ib[7] = Ib[6];

        const float4* v04 = (const float4*)(v0 + (size_t)b * 8);
        const float4* u04 = (const float4*)(u0 + (size_t)b * 8);
        float4 va = v04[0], vb4 = v04[1];
        float4 ua = u04[0], ub4 = u04[1];
        float v[8] = {va.x, va.y, va.z, va.w, vb4.x, vb4.y, vb4.z, vb4.w};
        float u[8] = {ua.x, ua.y, ua.z, ua.w, ub4.x, ub4.y, ub4.z, ub4.w};
        float rate[8] = {0, 0, 0, 0, 0, 0, 0, 0};

        #pragma unroll
        for (int s = 0; s < 10; ++s) {
            const float4* n4 =
                (const float4*)(noise + (size_t)s * (size_t)Bn * 8 + (size_t)b * 8);
            float4 na = n4[0], nb = n4[1];
            float eps[8] = {na.x, na.y, na.z, na.w, nb.x, nb.y, nb.z, nb.w};
            #pragma unroll
            for (int n = 0; n < 8; ++n) {
                float vv = v[n];
                float uu = u[n];
                float Iin = Ib[n] + eps[n] * 0.3f;
                vv = vv + (0.04f * vv * vv + 5.0f * vv + 140.0f - uu + Iin);
                uu = uu + 0.02f * (0.2f * vv - uu);
                bool sp = (vv >= 30.0f);
                v[n] = sp ? -65.0f : vv;
                u[n] = sp ? (uu + 8.0f) : uu;
                rate[n] = 0.9f * rate[n] + (sp ? 0.1f : 0.0f);
            }
        }

        float rate_sum = 0.0f;
        #pragma unroll
        for (int n = 0; n < 8; ++n) rate_sum += rate[n];
        float rate_mean = rate_sum * 0.125f;

        float norm_speed = fminf(1.0f, actual_speed / 4.0f);
        float e0 = norm_speed - ps;
        float e1 = heading_delta - phdd;
        float e2 = wall;   // prediction channel 2 is 0
        float e3 = coll;   // prediction channel 3 is 0

        float pe0 = e0;           // prec 1.0
        float pe1 = e1;           // prec 1.0
        float pe2 = 0.5f * e2;    // prec 0.5
        float pe3 = e3;           // prec 1.0
        float fe = 0.5f * (e0 * e0 + e1 * e1 + (0.5f * e2) * e2 + e3 * e3);

        r[0] = actual_speed;
        r[1] = heading_delta;
        r[2] = wall;
        r[3] = rate_mean;
        r[4] = pe0;
        r[5] = pe1;
        r[6] = pe2;
        r[7] = pe3;
        r[8] = fe;
    } else {
        #pragma unroll
        for (int k = 0; k < 9; ++k) r[k] = 0.0f;
    }

    // Stage [256 x 9] in LDS (stride 9 is odd -> conflict-free), flush coalesced.
    #pragma unroll
    for (int k = 0; k < 9; ++k) sout[t * 9 + k] = r[k];
    __syncthreads();

    size_t base = (size_t)blockIdx.x * (256 * 9);
    int remain = Bn - blockIdx.x * 256;
    if (remain >= 256) {
        float4* o4 = (float4*)(out + base);
        const float4* s4 = (const float4*)sout;
        #pragma unroll
        for (int i = 0; i < 3; ++i) {
            int idx = t + i * 256;
            if (idx < 576) o4[idx] = s4[idx];
        }
    } else if (remain > 0) {
        int nvalid = remain * 9;
        for (int i = t; i < nvalid; i += 256) out[base + i] = sout[i];
    }
}

extern "C" void kernel_launch(void* const* d_in, const int* in_sizes, int n_in,
                              void* d_out, int out_size, void* d_ws, size_t ws_size,
                              hipStream_t stream) {
    const float* fish_x       = (const float*)d_in[0];
    const float* fish_y       = (const float*)d_in[1];
    const float* speed        = (const float*)d_in[2];
    const float* heading      = (const float*)d_in[3];
    const float* prev_x       = (const float*)d_in[4];
    const float* prev_y       = (const float*)d_in[5];
    const float* prev_heading = (const float*)d_in[6];
    const float* pred_speed   = (const float*)d_in[7];
    const float* pred_hd      = (const float*)d_in[8];
    const float* v0           = (const float*)d_in[9];
    const float* u0           = (const float*)d_in[10];
    const float* noise        = (const float*)d_in[11];
    float* out = (float*)d_out;

    int Bn = in_sizes[0];
    int grid = (Bn + 255) / 256;
    spiking_fwd<<<grid, 256, 0, stream>>>(
        fish_x, fish_y, speed, heading, prev_x, prev_y, prev_heading,
        pred_speed, pred_hd, v0, u0, noise, out, Bn);
}

// Round 2
// 524.427 us; speedup vs baseline: 1.0256x; 1.0256x over previous
//
#include <hip/hip_runtime.h>
#include <math.h>

// Izhikevich RS constants (match reference)
// A=0.02, Bz=0.2, C=-65, D=8, I_TONIC=-1, V_PEAK=30, RATE_DECAY=0.9
// MARGIN=50, ARENA_W=800, ARENA_H=600, PRECISION=[1,1,0.5,1]

// __launch_bounds__(256,4): cap VGPR at 128 so we hold >=4 waves/SIMD
// (16 waves/CU). Rolled step-loop + 1-step prefetch keeps live state ~80 VGPR.
__global__ __launch_bounds__(256, 4) void spiking_fwd(
    const float* __restrict__ fish_x,
    const float* __restrict__ fish_y,
    const float* __restrict__ speed,
    const float* __restrict__ heading,
    const float* __restrict__ prev_x,
    const float* __restrict__ prev_y,
    const float* __restrict__ prev_heading,
    const float* __restrict__ pred_speed,
    const float* __restrict__ pred_hd,
    const float* __restrict__ v0,
    const float* __restrict__ u0,
    const float* __restrict__ noise,
    float* __restrict__ out,
    int Bn)
{
    __shared__ float sout[256 * 9];
    const int t = threadIdx.x;
    const int b = blockIdx.x * 256 + t;

    float r[9];
    if (b < Bn) {
        float fx  = fish_x[b],  fy  = fish_y[b];
        float spd = speed[b],   hdg = heading[b];
        float px  = prev_x[b],  py  = prev_y[b], phd = prev_heading[b];
        float ps  = pred_speed[b], phdd = pred_hd[b];

        float dx = fx - px, dy = fy - py;
        float actual_speed = sqrtf(dx * dx + dy * dy);

        float hd = hdg - phd;
        float heading_delta = atan2f(sinf(hd), cosf(hd));

        // max of relus == relu of max (relu is monotone)
        float wall = fmaxf(0.0f,
            fmaxf(fmaxf((50.0f - fx) / 50.0f, (fx - 750.0f) / 50.0f),
                  fmaxf((50.0f - fy) / 50.0f, (fy - 550.0f) / 50.0f)));

        float coll = (actual_speed < 1.0f && spd > 0.5f) ? 1.0f : 0.0f;

        // base currents with I_TONIC folded in
        float Ib[8];
        Ib[0] = actual_speed * 5.0f - 1.0f;
        Ib[1] = fmaxf(0.0f, 3.0f - actual_speed) * 3.0f - 1.0f;
        Ib[2] = (cosf(hdg) + 1.0f) * 3.0f - 1.0f;
        Ib[3] = (sinf(hdg) + 1.0f) * 3.0f - 1.0f;
        Ib[4] = wall * 12.0f - 1.0f;
        Ib[5] = Ib[4];
        Ib[6] = coll * 15.0f - 1.0f;
        Ib[7] = Ib[6];

        const float4* v04 = (const float4*)(v0 + (size_t)b * 8);
        const float4* u04 = (const float4*)(u0 + (size_t)b * 8);
        float4 va = v04[0], vb4 = v04[1];
        float4 ua = u04[0], ub4 = u04[1];
        float v[8] = {va.x, va.y, va.z, va.w, vb4.x, vb4.y, vb4.z, vb4.w};
        float u[8] = {ua.x, ua.y, ua.z, ua.w, ub4.x, ub4.y, ub4.z, ub4.w};
        float rate[8] = {0, 0, 0, 0, 0, 0, 0, 0};

        // Rolled loop with one-step prefetch: bounded VGPR, loads always in flight.
        const float* nbase = noise + (size_t)b * 8;
        const size_t sstride = (size_t)Bn * 8;
        float4 na = ((const float4*)nbase)[0];
        float4 nb = ((const float4*)nbase)[1];

        #pragma unroll 1
        for (int s = 0; s < 10; ++s) {
            float4 ca = na, cb = nb;
            if (s < 9) {  // wave-uniform branch
                const float* p = nbase + (size_t)(s + 1) * sstride;
                na = ((const float4*)p)[0];
                nb = ((const float4*)p)[1];
            }
            float eps[8] = {ca.x, ca.y, ca.z, ca.w, cb.x, cb.y, cb.z, cb.w};
            #pragma unroll
            for (int n = 0; n < 8; ++n) {
                float vv = v[n];
                float uu = u[n];
                float Iin = Ib[n] + eps[n] * 0.3f;
                vv = vv + (0.04f * vv * vv + 5.0f * vv + 140.0f - uu + Iin);
                uu = uu + 0.02f * (0.2f * vv - uu);
                bool sp = (vv >= 30.0f);
                v[n] = sp ? -65.0f : vv;
                u[n] = sp ? (uu + 8.0f) : uu;
                rate[n] = 0.9f * rate[n] + (sp ? 0.1f : 0.0f);
            }
        }

        float rate_sum = 0.0f;
        #pragma unroll
        for (int n = 0; n < 8; ++n) rate_sum += rate[n];
        float rate_mean = rate_sum * 0.125f;

        float norm_speed = fminf(1.0f, actual_speed / 4.0f);
        float e0 = norm_speed - ps;
        float e1 = heading_delta - phdd;
        float e2 = wall;   // prediction channel 2 is 0
        float e3 = coll;   // prediction channel 3 is 0

        float pe0 = e0;           // prec 1.0
        float pe1 = e1;           // prec 1.0
        float pe2 = 0.5f * e2;    // prec 0.5
        float pe3 = e3;           // prec 1.0
        float fe = 0.5f * (e0 * e0 + e1 * e1 + (0.5f * e2) * e2 + e3 * e3);

        r[0] = actual_speed;
        r[1] = heading_delta;
        r[2] = wall;
        r[3] = rate_mean;
        r[4] = pe0;
        r[5] = pe1;
        r[6] = pe2;
        r[7] = pe3;
        r[8] = fe;
    } else {
        #pragma unroll
        for (int k = 0; k < 9; ++k) r[k] = 0.0f;
    }

    // Stage [256 x 9] in LDS (stride 9 is odd -> conflict-free), flush coalesced.
    #pragma unroll
    for (int k = 0; k < 9; ++k) sout[t * 9 + k] = r[k];
    __syncthreads();

    size_t base = (size_t)blockIdx.x * (256 * 9);
    int remain = Bn - blockIdx.x * 256;
    if (remain >= 256) {
        float4* o4 = (float4*)(out + base);
        const float4* s4 = (const float4*)sout;
        #pragma unroll
        for (int i = 0; i < 3; ++i) {
            int idx = t + i * 256;
            if (idx < 576) o4[idx] = s4[idx];
        }
    } else if (remain > 0) {
        int nvalid = remain * 9;
        for (int i = t; i < nvalid; i += 256) out[base + i] = sout[i];
    }
}

extern "C" void kernel_launch(void* const* d_in, const int* in_sizes, int n_in,
                              void* d_out, int out_size, void* d_ws, size_t ws_size,
                              hipStream_t stream) {
    const float* fish_x       = (const float*)d_in[0];
    const float* fish_y       = (const float*)d_in[1];
    const float* speed        = (const float*)d_in[2];
    const float* heading      = (const float*)d_in[3];
    const float* prev_x       = (const float*)d_in[4];
    const float* prev_y       = (const float*)d_in[5];
    const float* prev_heading = (const float*)d_in[6];
    const float* pred_speed   = (const float*)d_in[7];
    const float* pred_hd      = (const float*)d_in[8];
    const float* v0           = (const float*)d_in[9];
    const float* u0           = (const float*)d_in[10];
    const float* noise        = (const float*)d_in[11];
    float* out = (float*)d_out;

    int Bn = in_sizes[0];
    int grid = (Bn + 255) / 256;
    spiking_fwd<<<grid, 256, 0, stream>>>(
        fish_x, fish_y, speed, heading, prev_x, prev_y, prev_heading,
        pred_speed, pred_hd, v0, u0, noise, out, Bn);
}

// Round 3
// 523.564 us; speedup vs baseline: 1.0272x; 1.0016x over previous
//
#include <hip/hip_runtime.h>
#include <math.h>

// Izhikevich RS constants (match reference)
// A=0.02, Bz=0.2, C=-65, D=8, I_TONIC=-1, V_PEAK=30, RATE_DECAY=0.9
// MARGIN=50, ARENA_W=800, ARENA_H=600, PRECISION=[1,1,0.5,1]
//
// R3: (a) atan2f(sinf,cosf) -> rintf wrap identity; sinf/cosf -> __sincosf
//     (kills libm VGPR bloat + slow paths); (b) 2-deep noise prefetch
//     (4 KB in flight per wave); (c) __launch_bounds__(256,5) -> VGPR<=102,
//     20 waves/CU. Goal: memory-level parallelism to reach the HBM floor.

__global__ __launch_bounds__(256, 5) void spiking_fwd(
    const float* __restrict__ fish_x,
    const float* __restrict__ fish_y,
    const float* __restrict__ speed,
    const float* __restrict__ heading,
    const float* __restrict__ prev_x,
    const float* __restrict__ prev_y,
    const float* __restrict__ prev_heading,
    const float* __restrict__ pred_speed,
    const float* __restrict__ pred_hd,
    const float* __restrict__ v0,
    const float* __restrict__ u0,
    const float* __restrict__ noise,
    float* __restrict__ out,
    int Bn)
{
    __shared__ float sout[256 * 9];
    const int t = threadIdx.x;
    const int b = blockIdx.x * 256 + t;

    float r[9];
    if (b < Bn) {
        // Issue the state + first two noise-step loads as early as possible.
        const float4* v04 = (const float4*)(v0 + (size_t)b * 8);
        const float4* u04 = (const float4*)(u0 + (size_t)b * 8);
        const float* nbase = noise + (size_t)b * 8;
        const size_t sstride = (size_t)Bn * 8;

        float4 va = v04[0], vb4 = v04[1];
        float4 ua = u04[0], ub4 = u04[1];
        float4 p0a = ((const float4*)nbase)[0];
        float4 p0b = ((const float4*)nbase)[1];
        float4 p1a = ((const float4*)(nbase + sstride))[0];
        float4 p1b = ((const float4*)(nbase + sstride))[1];

        float fx  = fish_x[b],  fy  = fish_y[b];
        float spd = speed[b],   hdg = heading[b];
        float px  = prev_x[b],  py  = prev_y[b], phd = prev_heading[b];
        float ps  = pred_speed[b], phdd = pred_hd[b];

        float dx = fx - px, dy = fy - py;
        float actual_speed = sqrtf(dx * dx + dy * dy);

        // atan2(sin(hd), cos(hd)) == wrap hd to (-pi, pi]
        float hd = hdg - phd;
        float heading_delta = hd - 6.28318530717958648f *
                              rintf(hd * 0.159154943091895336f);

        float wall = fmaxf(0.0f,
            fmaxf(fmaxf((50.0f - fx) / 50.0f, (fx - 750.0f) / 50.0f),
                  fmaxf((50.0f - fy) / 50.0f, (fy - 550.0f) / 50.0f)));

        float coll = (actual_speed < 1.0f && spd > 0.5f) ? 1.0f : 0.0f;

        float sh, ch;
        __sincosf(hdg, &sh, &ch);

        // IbT[n] = base current + I_TONIC + 140  (folded into v-update addend)
        float IbT[8];
        IbT[0] = actual_speed * 5.0f + 139.0f;
        IbT[1] = fmaxf(0.0f, 3.0f - actual_speed) * 3.0f + 139.0f;
        IbT[2] = (ch + 1.0f) * 3.0f + 139.0f;
        IbT[3] = (sh + 1.0f) * 3.0f + 139.0f;
        IbT[4] = wall * 12.0f + 139.0f;
        IbT[5] = IbT[4];
        IbT[6] = coll * 15.0f + 139.0f;
        IbT[7] = IbT[6];

        float v[8] = {va.x, va.y, va.z, va.w, vb4.x, vb4.y, vb4.z, vb4.w};
        float u[8] = {ua.x, ua.y, ua.z, ua.w, ub4.x, ub4.y, ub4.z, ub4.w};
        float rate[8] = {0, 0, 0, 0, 0, 0, 0, 0};

        auto stepf = [&](const float4& ea, const float4& eb) {
            float eps[8] = {ea.x, ea.y, ea.z, ea.w, eb.x, eb.y, eb.z, eb.w};
            #pragma unroll
            for (int n = 0; n < 8; ++n) {
                float P  = fmaf(0.3f, eps[n], IbT[n]) - u[n];
                float vv = fmaf(v[n], fmaf(0.04f, v[n], 6.0f), P);
                float uu = fmaf(0.02f, fmaf(0.2f, vv, -u[n]), u[n]);
                bool sp = (vv >= 30.0f);
                v[n] = sp ? -65.0f : vv;
                u[n] = sp ? (uu + 8.0f) : uu;
                rate[n] = fmaf(0.9f, rate[n], sp ? 0.1f : 0.0f);
            }
        };

        // 2-deep rotating prefetch: up to 4 float4 loads (4 KB/wave) in flight.
        #pragma unroll 1
        for (int s = 0; s < 10; s += 2) {
            float4 ca = p0a, cb = p0b;
            if (s < 8) {
                const float* p = nbase + (size_t)(s + 2) * sstride;
                p0a = ((const float4*)p)[0];
                p0b = ((const float4*)p)[1];
            }
            stepf(ca, cb);
            float4 da = p1a, db = p1b;
            if (s < 8) {
                const float* p = nbase + (size_t)(s + 3) * sstride;
                p1a = ((const float4*)p)[0];
                p1b = ((const float4*)p)[1];
            }
            stepf(da, db);
        }

        float rate_sum = 0.0f;
        #pragma unroll
        for (int n = 0; n < 8; ++n) rate_sum += rate[n];
        float rate_mean = rate_sum * 0.125f;

        float norm_speed = fminf(1.0f, actual_speed * 0.25f);
        float e0 = norm_speed - ps;
        float e1 = heading_delta - phdd;
        float e2 = wall;
        float e3 = coll;

        float fe = 0.5f * (e0 * e0 + e1 * e1 + (0.5f * e2) * e2 + e3 * e3);

        r[0] = actual_speed;
        r[1] = heading_delta;
        r[2] = wall;
        r[3] = rate_mean;
        r[4] = e0;
        r[5] = e1;
        r[6] = 0.5f * e2;
        r[7] = e3;
        r[8] = fe;
    } else {
        #pragma unroll
        for (int k = 0; k < 9; ++k) r[k] = 0.0f;
    }

    // Stage [256 x 9] in LDS (stride 9 odd -> conflict-free), flush coalesced.
    #pragma unroll
    for (int k = 0; k < 9; ++k) sout[t * 9 + k] = r[k];
    __syncthreads();

    size_t base = (size_t)blockIdx.x * (256 * 9);
    int remain = Bn - blockIdx.x * 256;
    if (remain >= 256) {
        float4* o4 = (float4*)(out + base);
        const float4* s4 = (const float4*)sout;
        #pragma unroll
        for (int i = 0; i < 3; ++i) {
            int idx = t + i * 256;
            if (idx < 576) o4[idx] = s4[idx];
        }
    } else if (remain > 0) {
        int nvalid = remain * 9;
        for (int i = t; i < nvalid; i += 256) out[base + i] = sout[i];
    }
}

extern "C" void kernel_launch(void* const* d_in, const int* in_sizes, int n_in,
                              void* d_out, int out_size, void* d_ws, size_t ws_size,
                              hipStream_t stream) {
    const float* fish_x       = (const float*)d_in[0];
    const float* fish_y       = (const float*)d_in[1];
    const float* speed        = (const float*)d_in[2];
    const float* heading      = (const float*)d_in[3];
    const float* prev_x       = (const float*)d_in[4];
    const float* prev_y       = (const float*)d_in[5];
    const float* prev_heading = (const float*)d_in[6];
    const float* pred_speed   = (const float*)d_in[7];
    const float* pred_hd      = (const float*)d_in[8];
    const float* v0           = (const float*)d_in[9];
    const float* u0           = (const float*)d_in[10];
    const float* noise        = (const float*)d_in[11];
    float* out = (float*)d_out;

    int Bn = in_sizes[0];
    int grid = (Bn + 255) / 256;
    spiking_fwd<<<grid, 256, 0, stream>>>(
        fish_x, fish_y, speed, heading, prev_x, prev_y, prev_heading,
        pred_speed, pred_hd, v0, u0, noise, out, Bn);
}